// Round 9
// baseline (169.642 us; speedup 1.0000x reference)
//
#include <hip/hip_runtime.h>
#include <stdint.h>

// Problem constants (B=4, C=256, C8=32, H=W=64, N=4096)
#define NB 4
#define NC 256
#define NN 4096

typedef __attribute__((ext_vector_type(8))) short bf16x8;
typedef __attribute__((ext_vector_type(4))) float f32x4;
typedef __attribute__((ext_vector_type(16))) float f32x16;
typedef __attribute__((ext_vector_type(8))) unsigned short u16x8;
typedef __attribute__((ext_vector_type(4))) unsigned short u16x4;
typedef __attribute__((ext_vector_type(4))) unsigned int u32x4;

#define MFMA32(a, b, c) __builtin_amdgcn_mfma_f32_32x32x16_bf16((a), (b), (c), 0, 0, 0)
#define LOG2E 1.4426950408889634f

__device__ __forceinline__ unsigned short bf16_rne(float f) {
    unsigned int u = __builtin_bit_cast(unsigned int, f);
    u += 0x7fffu + ((u >> 16) & 1u);
    return (unsigned short)(u >> 16);
}
__device__ __forceinline__ float bf16_to_f(unsigned short h) {
    return __builtin_bit_cast(float, (unsigned int)h << 16);
}
__device__ __forceinline__ float exp2_hw(float x) {
    float r;
    asm("v_exp_f32 %0, %1" : "=v"(r) : "v"(x));
    return r;
}
__device__ __forceinline__ unsigned int cvtpk_bf16(float lo, float hi) {
    unsigned int r;
    asm("v_cvt_pk_bf16_f32 %0, %1, %2" : "=v"(r) : "v"(lo), "v"(hi));
    return r;
}

__device__ __forceinline__ void async16(const void* g, void* l) {
    __builtin_amdgcn_global_load_lds(
        (const __attribute__((address_space(1))) unsigned int*)g,
        (__attribute__((address_space(3))) unsigned int*)l, 16, 0, 0);
}

// ---------------------------------------------------------------------------
// Projection kernel (R2 version, verbatim — measured 52.8 us): q,k (fp32 ->
// bf16 hi/lo split) and v (bf16), BN folded; q scaled by log2(e) for exp2.
// q_hi/q_lo/k_hi/k_lo layout: [B][N][32] bf16 ; v layout: [B][256][N] bf16.
// Grid: 512 blocks x 256 threads; block handles 32 spatial positions.
// ---------------------------------------------------------------------------
__global__ __launch_bounds__(256) void proj_kernel(
    const float* __restrict__ x,
    const float* __restrict__ wq,
    const float* __restrict__ qg, const float* __restrict__ qb,
    const float* __restrict__ qm, const float* __restrict__ qv,
    const float* __restrict__ wk,
    const float* __restrict__ kg, const float* __restrict__ kb,
    const float* __restrict__ km, const float* __restrict__ kv,
    const float* __restrict__ wv,
    const float* __restrict__ vg, const float* __restrict__ vb,
    const float* __restrict__ vm, const float* __restrict__ vv,
    unsigned short* __restrict__ qhi, unsigned short* __restrict__ qlo,
    unsigned short* __restrict__ khi, unsigned short* __restrict__ klo,
    unsigned short* __restrict__ vws)
{
    __shared__ float xt[NC * 36 + 8];
    const int t = threadIdx.x;
    const int blk = blockIdx.x;
    const int b = blk >> 7;
    const int n0 = (blk & 127) << 5;
    const float* xb = x + ((size_t)b << 20);

    for (int idx = t; idx < NC * 32; idx += 256) {
        int c = idx >> 5, j = idx & 31;
        xt[c * 36 + j] = xb[((size_t)c << 12) + n0 + j];
    }
    __syncthreads();

    {
        const int p = t & 31;
        const int og = t >> 5;
        const bool is_k = og >= 4;
        const int o0 = (og & 3) << 3;
        const float* w = is_k ? wk : wq;
        float acc[8];
#pragma unroll
        for (int o = 0; o < 8; ++o) acc[o] = 0.f;
        for (int c4 = 0; c4 < NC; c4 += 4) {
            float x0 = xt[(c4 + 0) * 36 + p];
            float x1 = xt[(c4 + 1) * 36 + p];
            float x2 = xt[(c4 + 2) * 36 + p];
            float x3 = xt[(c4 + 3) * 36 + p];
#pragma unroll
            for (int o = 0; o < 8; ++o) {
                const float4 w4 = *(const float4*)&w[(o0 + o) * NC + c4];
                acc[o] += w4.x * x0 + w4.y * x1 + w4.z * x2 + w4.w * x3;
            }
        }
        const float* G = is_k ? kg : qg;
        const float* Bb = is_k ? kb : qb;
        const float* M = is_k ? km : qm;
        const float* V = is_k ? kv : qv;
        u16x8 hv, lv;
#pragma unroll
        for (int o = 0; o < 8; ++o) {
            int oo = o0 + o;
            float sc = G[oo] / sqrtf(V[oo] + 1e-5f);
            float val = acc[o] * sc + (Bb[oo] - M[oo] * sc);
            if (!is_k) val *= LOG2E;
            unsigned short h = bf16_rne(val);
            hv[o] = h;
            lv[o] = bf16_rne(val - bf16_to_f(h));
        }
        size_t base = ((size_t)(b << 12) + n0 + p) * 32 + o0;
        *(u16x8*)&(is_k ? khi : qhi)[base] = hv;
        *(u16x8*)&(is_k ? klo : qlo)[base] = lv;
    }

    {
        const int p4 = (t & 7) << 2;
        const int og = t >> 3;
        const int o0 = og << 3;
        float acc[4][8];
#pragma unroll
        for (int pp = 0; pp < 4; ++pp)
#pragma unroll
            for (int o = 0; o < 8; ++o) acc[pp][o] = 0.f;
        for (int c4 = 0; c4 < NC; c4 += 4) {
            float4 xv0 = *(const float4*)&xt[(c4 + 0) * 36 + p4];
            float4 xv1 = *(const float4*)&xt[(c4 + 1) * 36 + p4];
            float4 xv2 = *(const float4*)&xt[(c4 + 2) * 36 + p4];
            float4 xv3 = *(const float4*)&xt[(c4 + 3) * 36 + p4];
#pragma unroll
            for (int o = 0; o < 8; ++o) {
                const float4 w4 = *(const float4*)&wv[(o0 + o) * NC + c4];
                acc[0][o] += w4.x * xv0.x + w4.y * xv1.x + w4.z * xv2.x + w4.w * xv3.x;
                acc[1][o] += w4.x * xv0.y + w4.y * xv1.y + w4.z * xv2.y + w4.w * xv3.y;
                acc[2][o] += w4.x * xv0.z + w4.y * xv1.z + w4.z * xv2.z + w4.w * xv3.z;
                acc[3][o] += w4.x * xv0.w + w4.y * xv1.w + w4.z * xv2.w + w4.w * xv3.w;
            }
        }
#pragma unroll
        for (int o = 0; o < 8; ++o) {
            int oo = o0 + o;
            float sc = vg[oo] / sqrtf(vv[oo] + 1e-5f);
            float sh = vb[oo] - vm[oo] * sc;
            u16x4 st;
#pragma unroll
            for (int pp = 0; pp < 4; ++pp) st[pp] = bf16_rne(acc[pp][o] * sc + sh);
            *(u16x4*)&vws[((size_t)(b * NC + oo) << 12) + n0 + p4] = st;
        }
    }
}

// ---------------------------------------------------------------------------
// Flash attention v7: R8 decomposition (512 x 256, 4 waves = 2 wc x 2 wjp,
// 32x32x16) with K DIRECT FROM GLOBAL (L2-hot) into registers, software-
// pipelined one jt ahead (unroll-2 for static cur/nxt). kmap (bit2<->3 swap)
// moves into the K global address; K LDS staging + swizzle deleted.
// LDS: 2 x 32KB V-only staging (XOR-swizzled via global source) + 1KB ml.
// Per block-jt: 32 chunk-writes + 32 ds_read_b128 (was 40 + 48).
// ---------------------------------------------------------------------------
__global__ __launch_bounds__(256, 2) void attn_kernel(
    const float* __restrict__ x, const float* __restrict__ gamma_p,
    const unsigned short* __restrict__ qhi, const unsigned short* __restrict__ qlo,
    const unsigned short* __restrict__ khi, const unsigned short* __restrict__ klo,
    const unsigned short* __restrict__ vws,
    float* __restrict__ out)
{
    __shared__ __align__(16) char smem[66560];
    const int t = threadIdx.x;
    const int pb = blockIdx.x;
    const int xcd = pb & 7;
    const int b = xcd >> 1;
    const int tile = ((xcd & 1) << 6) + (pb >> 3);
    const int i0 = tile << 5;
    const int w = t >> 6, lane = t & 63;
    const int h = lane >> 5, il = lane & 31;
    const int wc = w & 1, wjp = w >> 1;

    const size_t bN32 = (size_t)b * (NN * 32);
    const unsigned short* kh_g = khi + bN32;
    const unsigned short* kl_g = klo + bN32;
    const unsigned short* v_g = vws + (size_t)b * (NC * NN);

    // Q B-frags: lane holds Q[i = i0+il][c = ks*16 + h*8 + e], hi/lo
    bf16x8 qh[2], ql[2];
    {
        size_t qoff = bN32 + (size_t)(i0 + il) * 32 + h * 8;
        qh[0] = *(const bf16x8*)&qhi[qoff];
        ql[0] = *(const bf16x8*)&qlo[qoff];
        qh[1] = *(const bf16x8*)&qhi[qoff + 16];
        ql[1] = *(const bf16x8*)&qlo[qoff + 16];
    }

    // K A-frag row for this lane: S^T row (wjp*32+il) <-> global row kmap(il)
    // (kmap = swap bits 2<->3; keeps P b-frag j-order == V k-slot order).
    size_t krow;
    {
        int u = il;
        int kmp = (u & 0x13) | ((u & 4) << 1) | ((u & 8) >> 1);
        krow = ((size_t)(wjp * 32 + kmp) * 32) + h * 8;   // + j0*32 per jt
    }

    f32x16 acc[4];
#pragma unroll
    for (int fc = 0; fc < 4; ++fc)
#pragma unroll
        for (int e = 0; e < 16; ++e) acc[fc][e] = 0.f;
    float m_run = -3.0e38f, l_part = 0.f;   // per lane: q-row i = il

    // stage one 64-j V tile (32 chunks of 1KB). V 16B-slots XOR (c&7) via
    // pre-swizzled global source (rule 21), LDS dest linear.
    auto stage = [&](int jt, int bufi) {
        char* base = smem + bufi * 32768;
        const int j0 = jt << 6;
#pragma unroll
        for (int ci = 0; ci < 8; ++ci) {
            const int cidx = w + ci * 4;
            int c = (cidx << 3) + (lane >> 3);           // c-row 0..255
            int jslot = (lane & 7) ^ (c & 7);
            async16(v_g + ((size_t)c << 12) + j0 + (jslot << 3),
                    base + cidx * 1024);
        }
    };

    // K register fetch for tile jt into kr[4]: [0,1]=hi ks0/1, [2,3]=lo ks0/1
    auto kfetch = [&](int jt, bf16x8* kr) {
        const size_t rb = krow + (size_t)(jt << 6) * 32;
        kr[0] = *(const bf16x8*)&kh_g[rb];
        kr[1] = *(const bf16x8*)&kh_g[rb + 16];
        kr[2] = *(const bf16x8*)&kl_g[rb];
        kr[3] = *(const bf16x8*)&kl_g[rb + 16];
    };

    bf16x8 kreg[2][4];
    kfetch(0, kreg[0]);
    stage(0, 0);
    __syncthreads();

#pragma unroll 2
    for (int jt = 0; jt < NN / 64; ++jt) {
        const int cb = jt & 1;
        if (jt < NN / 64 - 1) {
            kfetch(jt + 1, kreg[cb ^ 1]);
            stage(jt + 1, cb ^ 1);
        }

        const unsigned short* Vl = (const unsigned short*)(smem + cb * 32768);

        // ---- S^T = K·Q (32x32, hi/lo, log2 domain): D[j-row][i = il] ----
        f32x16 s2;
#pragma unroll
        for (int e = 0; e < 16; ++e) s2[e] = 0.f;
#pragma unroll
        for (int ks = 0; ks < 2; ++ks) {
            s2 = MFMA32(kreg[cb][2 + ks], qh[ks], s2);
            s2 = MFMA32(kreg[cb][ks], ql[ks], s2);
            s2 = MFMA32(kreg[cb][ks], qh[ks], s2);
        }

        // ---- online softmax (row i = il; halves combined via xor-32) ----
        float tl = s2[0];
#pragma unroll
        for (int e = 1; e < 16; ++e) tl = fmaxf(tl, s2[e]);
        tl = fmaxf(tl, __shfl_xor(tl, 32));

        if (!__all(tl <= m_run + 11.0f)) {
            float nm = fmaxf(m_run, tl);
            float rs = exp2_hw(m_run - nm);
            m_run = nm;
            l_part *= rs;
#pragma unroll
            for (int fc = 0; fc < 4; ++fc)
#pragma unroll
                for (int e = 0; e < 16; ++e) acc[fc][e] *= rs;
        }

        float p[16];
#pragma unroll
        for (int e = 0; e < 16; ++e) p[e] = exp2_hw(s2[e] - m_run);
        float ls = 0.f;
#pragma unroll
        for (int e = 0; e < 16; ++e) ls += p[e];
        ls += __shfl_xor(ls, 32);
        l_part += ls;

        // ---- P -> bf16 B-frags (j-order already correct via kmap) ----
        bf16x8 pa[2];
#pragma unroll
        for (int ks = 0; ks < 2; ++ks) {
            u32x4 pw;
            pw[0] = cvtpk_bf16(p[ks * 8 + 0], p[ks * 8 + 1]);
            pw[1] = cvtpk_bf16(p[ks * 8 + 2], p[ks * 8 + 3]);
            pw[2] = cvtpk_bf16(p[ks * 8 + 4], p[ks * 8 + 5]);
            pw[3] = cvtpk_bf16(p[ks * 8 + 6], p[ks * 8 + 7]);
            pa[ks] = __builtin_bit_cast(bf16x8, pw);
        }

        // ---- PV: acc[fc] = V[c][j] (A) x P[j][i] (B), D[c-row][i-col] ----
#pragma unroll
        for (int fc = 0; fc < 4; ++fc) {
            const int c = wc * 128 + fc * 32 + il;
#pragma unroll
            for (int ks = 0; ks < 2; ++ks) {
                const int voff = c * 64 + ((((wjp << 2) + (ks << 1) + h) ^ (c & 7)) << 3);
                bf16x8 vbf = *(const bf16x8*)&Vl[voff];
                acc[fc] = MFMA32(vbf, pa[ks], acc[fc]);
            }
        }
        __syncthreads();   // drains stage(jt+1) + protects buffer swap
    }

    // ---- merge wjp partials, normalize, residual-add, store ----
    float* ml = (float*)(smem + 65536);       // m: [w*32+i], l: [128 + w*32+i]
    if (lane < 32) {
        ml[w * 32 + il] = m_run;
        ml[128 + w * 32 + il] = l_part;
    }
    __syncthreads();

    const int wp = w ^ 2;                     // partner wave (wjp flipped)
    float m_o = ml[wp * 32 + il];
    float l_o = ml[128 + wp * 32 + il];
    float m_g = fmaxf(m_run, m_o);
    float a_s = exp2_hw(m_run - m_g);
    float l_tot = l_part * a_s + l_o * exp2_hw(m_o - m_g);
#pragma unroll
    for (int fc = 0; fc < 4; ++fc)
#pragma unroll
        for (int e = 0; e < 16; ++e) acc[fc][e] *= a_s;

    float* AB = (float*)smem;                 // [256 c][32 i], over buf A
    if (wjp == 1) {
#pragma unroll
        for (int fc = 0; fc < 4; ++fc)
#pragma unroll
            for (int e = 0; e < 16; ++e) {
                int c = wc * 128 + fc * 32 + (e & 3) + 8 * (e >> 2) + 4 * h;
                AB[c * 32 + il] = acc[fc][e];
            }
    }
    __syncthreads();

    float* ep = (float*)(smem + 32768);       // [256 c][32 i], over buf B
    if (wjp == 0) {
        const float gm = gamma_p[0];
        const float linv = gm / l_tot;
#pragma unroll
        for (int fc = 0; fc < 4; ++fc)
#pragma unroll
            for (int e = 0; e < 16; ++e) {
                int c = wc * 128 + fc * 32 + (e & 3) + 8 * (e >> 2) + 4 * h;
                ep[c * 32 + il] = (acc[fc][e] + AB[c * 32 + il]) * linv;
            }
    }
    __syncthreads();

    const float* xb = x + ((size_t)b << 20);
    float* ob = out + ((size_t)b << 20);
#pragma unroll
    for (int it = 0; it < 8; ++it) {
        int c = (t >> 3) + (it << 5);
        int j = t & 7;
        f32x4 v = *(const f32x4*)&ep[c * 32 + j * 4];
        f32x4 xv = *(const f32x4*)&xb[((size_t)c << 12) + i0 + j * 4];
        v += xv;
        *(f32x4*)&ob[((size_t)c << 12) + i0 + j * 4] = v;
    }
}

// ---------------------------------------------------------------------------
extern "C" void kernel_launch(void* const* d_in, const int* in_sizes, int n_in,
                              void* d_out, int out_size, void* d_ws, size_t ws_size,
                              hipStream_t stream)
{
    (void)in_sizes; (void)n_in; (void)out_size; (void)ws_size;
    const float* x = (const float*)d_in[0];
    const float* wq = (const float*)d_in[1];
    const float* qg = (const float*)d_in[2];
    const float* qb = (const float*)d_in[3];
    const float* qm = (const float*)d_in[4];
    const float* qv = (const float*)d_in[5];
    const float* wk = (const float*)d_in[6];
    const float* kg = (const float*)d_in[7];
    const float* kb = (const float*)d_in[8];
    const float* km = (const float*)d_in[9];
    const float* kv = (const float*)d_in[10];
    const float* wv = (const float*)d_in[11];
    const float* vg = (const float*)d_in[12];
    const float* vb = (const float*)d_in[13];
    const float* vm = (const float*)d_in[14];
    const float* vv = (const float*)d_in[15];
    const float* gamma = (const float*)d_in[16];

    unsigned short* ws = (unsigned short*)d_ws;
    const size_t QK = (size_t)NB * NN * 32;
    unsigned short* qhi = ws;
    unsigned short* qlo = ws + QK;
    unsigned short* khi = ws + 2 * QK;
    unsigned short* klo = ws + 3 * QK;
    unsigned short* vws = ws + 4 * QK;

    proj_kernel<<<dim3(512), dim3(256), 0, stream>>>(
        x, wq, qg, qb, qm, qv, wk, kg, kb, km, kv, wv, vg, vb, vm, vv,
        qhi, qlo, khi, klo, vws);
    attn_kernel<<<dim3(512), dim3(256), 0, stream>>>(
        x, gamma, qhi, qlo, khi, klo, vws, (float*)d_out);
}

// Round 10
// 158.262 us; speedup vs baseline: 1.0719x; 1.0719x over previous
//
#include <hip/hip_runtime.h>
#include <stdint.h>

// Problem constants (B=4, C=256, C8=32, H=W=64, N=4096)
#define NB 4
#define NC 256
#define NN 4096

typedef __attribute__((ext_vector_type(8))) short bf16x8;
typedef __attribute__((ext_vector_type(4))) float f32x4;
typedef __attribute__((ext_vector_type(16))) float f32x16;
typedef __attribute__((ext_vector_type(8))) unsigned short u16x8;
typedef __attribute__((ext_vector_type(4))) unsigned short u16x4;
typedef __attribute__((ext_vector_type(4))) unsigned int u32x4;

#define MFMA32(a, b, c) __builtin_amdgcn_mfma_f32_32x32x16_bf16((a), (b), (c), 0, 0, 0)
#define LOG2E 1.4426950408889634f

__device__ __forceinline__ unsigned short bf16_rne(float f) {
    unsigned int u = __builtin_bit_cast(unsigned int, f);
    u += 0x7fffu + ((u >> 16) & 1u);
    return (unsigned short)(u >> 16);
}
__device__ __forceinline__ float bf16_to_f(unsigned short h) {
    return __builtin_bit_cast(float, (unsigned int)h << 16);
}
__device__ __forceinline__ float exp2_hw(float x) {
    float r;
    asm("v_exp_f32 %0, %1" : "=v"(r) : "v"(x));
    return r;
}
__device__ __forceinline__ unsigned int cvtpk_bf16(float lo, float hi) {
    unsigned int r;
    asm("v_cvt_pk_bf16_f32 %0, %1, %2" : "=v"(r) : "v"(lo), "v"(hi));
    return r;
}

// ---------------------------------------------------------------------------
// Projection kernel (R2 structure; only the v-store layout changed):
// q,k (fp32 -> bf16 hi/lo split) and v (bf16), BN folded; q scaled by log2(e).
// q_hi/q_lo/k_hi/k_lo layout: [B][N][32] bf16.
// v layout (NEW, PV-fragment order): [B][jg = N/8][c = 256][8 j] bf16, so a
// PV A-frag is one coalesced b128 global load in the attention kernel.
// Grid: 512 blocks x 256 threads; block handles 32 spatial positions.
// ---------------------------------------------------------------------------
__global__ __launch_bounds__(256) void proj_kernel(
    const float* __restrict__ x,
    const float* __restrict__ wq,
    const float* __restrict__ qg, const float* __restrict__ qb,
    const float* __restrict__ qm, const float* __restrict__ qv,
    const float* __restrict__ wk,
    const float* __restrict__ kg, const float* __restrict__ kb,
    const float* __restrict__ km, const float* __restrict__ kv,
    const float* __restrict__ wv,
    const float* __restrict__ vg, const float* __restrict__ vb,
    const float* __restrict__ vm, const float* __restrict__ vv,
    unsigned short* __restrict__ qhi, unsigned short* __restrict__ qlo,
    unsigned short* __restrict__ khi, unsigned short* __restrict__ klo,
    unsigned short* __restrict__ vws)
{
    __shared__ float xt[NC * 36 + 8];
    const int t = threadIdx.x;
    const int blk = blockIdx.x;
    const int b = blk >> 7;
    const int n0 = (blk & 127) << 5;
    const float* xb = x + ((size_t)b << 20);

    for (int idx = t; idx < NC * 32; idx += 256) {
        int c = idx >> 5, j = idx & 31;
        xt[c * 36 + j] = xb[((size_t)c << 12) + n0 + j];
    }
    __syncthreads();

    {
        const int p = t & 31;
        const int og = t >> 5;
        const bool is_k = og >= 4;
        const int o0 = (og & 3) << 3;
        const float* w = is_k ? wk : wq;
        float acc[8];
#pragma unroll
        for (int o = 0; o < 8; ++o) acc[o] = 0.f;
        for (int c4 = 0; c4 < NC; c4 += 4) {
            float x0 = xt[(c4 + 0) * 36 + p];
            float x1 = xt[(c4 + 1) * 36 + p];
            float x2 = xt[(c4 + 2) * 36 + p];
            float x3 = xt[(c4 + 3) * 36 + p];
#pragma unroll
            for (int o = 0; o < 8; ++o) {
                const float4 w4 = *(const float4*)&w[(o0 + o) * NC + c4];
                acc[o] += w4.x * x0 + w4.y * x1 + w4.z * x2 + w4.w * x3;
            }
        }
        const float* G = is_k ? kg : qg;
        const float* Bb = is_k ? kb : qb;
        const float* M = is_k ? km : qm;
        const float* V = is_k ? kv : qv;
        u16x8 hv, lv;
#pragma unroll
        for (int o = 0; o < 8; ++o) {
            int oo = o0 + o;
            float sc = G[oo] / sqrtf(V[oo] + 1e-5f);
            float val = acc[o] * sc + (Bb[oo] - M[oo] * sc);
            if (!is_k) val *= LOG2E;
            unsigned short h = bf16_rne(val);
            hv[o] = h;
            lv[o] = bf16_rne(val - bf16_to_f(h));
        }
        size_t base = ((size_t)(b << 12) + n0 + p) * 32 + o0;
        *(u16x8*)&(is_k ? khi : qhi)[base] = hv;
        *(u16x8*)&(is_k ? klo : qlo)[base] = lv;
    }

    {
        const int p4 = (t & 7) << 2;
        const int og = t >> 3;
        const int o0 = og << 3;
        float acc[4][8];
#pragma unroll
        for (int pp = 0; pp < 4; ++pp)
#pragma unroll
            for (int o = 0; o < 8; ++o) acc[pp][o] = 0.f;
        for (int c4 = 0; c4 < NC; c4 += 4) {
            float4 xv0 = *(const float4*)&xt[(c4 + 0) * 36 + p4];
            float4 xv1 = *(const float4*)&xt[(c4 + 1) * 36 + p4];
            float4 xv2 = *(const float4*)&xt[(c4 + 2) * 36 + p4];
            float4 xv3 = *(const float4*)&xt[(c4 + 3) * 36 + p4];
#pragma unroll
            for (int o = 0; o < 8; ++o) {
                const float4 w4 = *(const float4*)&wv[(o0 + o) * NC + c4];
                acc[0][o] += w4.x * xv0.x + w4.y * xv1.x + w4.z * xv2.x + w4.w * xv3.x;
                acc[1][o] += w4.x * xv0.y + w4.y * xv1.y + w4.z * xv2.y + w4.w * xv3.y;
                acc[2][o] += w4.x * xv0.z + w4.y * xv1.z + w4.z * xv2.z + w4.w * xv3.z;
                acc[3][o] += w4.x * xv0.w + w4.y * xv1.w + w4.z * xv2.w + w4.w * xv3.w;
            }
        }
#pragma unroll
        for (int o = 0; o < 8; ++o) {
            int oo = o0 + o;
            float sc = vg[oo] / sqrtf(vv[oo] + 1e-5f);
            float sh = vb[oo] - vm[oo] * sc;
            u16x4 st;
#pragma unroll
            for (int pp = 0; pp < 4; ++pp) st[pp] = bf16_rne(acc[pp][o] * sc + sh);
            // V' layout: [b][jg][c][8j]; p4 is 0 or 4 within the 8-group.
            size_t jg = (size_t)((n0 + p4) >> 3);
            *(u16x4*)&vws[(((size_t)b * (NN / 8) + jg) * NC + oo) * 8 + (p4 & 7)] = st;
        }
    }
}

// ---------------------------------------------------------------------------
// Flash attention v8: ZERO LDS / ZERO barriers in the main loop. K and V both
// direct-from-global (L2-hot) into registers; V pre-fragmented by proj so each
// PV A-frag is one coalesced b128 load. kmap (bit2<->3 swap) in the K address
// keeps P's b-frag j-order == V' jgroup order (algebra re-verified).
// 512 blocks x 256 threads, 4 waves = 2 wc x 2 wjp, 32x32x16 MFMA.
// vfetch(jt) issued at body top (lands under QK+softmax); kfetch(jt+1)
// double-buffered via unroll-2. LDS only for the epilogue merge (66KB).
// ---------------------------------------------------------------------------
__global__ __launch_bounds__(256, 2) void attn_kernel(
    const float* __restrict__ x, const float* __restrict__ gamma_p,
    const unsigned short* __restrict__ qhi, const unsigned short* __restrict__ qlo,
    const unsigned short* __restrict__ khi, const unsigned short* __restrict__ klo,
    const unsigned short* __restrict__ vws,
    float* __restrict__ out)
{
    __shared__ __align__(16) char smem[66560];
    const int t = threadIdx.x;
    const int pb = blockIdx.x;
    const int xcd = pb & 7;
    const int b = xcd >> 1;
    const int tile = ((xcd & 1) << 6) + (pb >> 3);
    const int i0 = tile << 5;
    const int w = t >> 6, lane = t & 63;
    const int h = lane >> 5, il = lane & 31;
    const int wc = w & 1, wjp = w >> 1;

    const size_t bN32 = (size_t)b * (NN * 32);
    const unsigned short* kh_g = khi + bN32;
    const unsigned short* kl_g = klo + bN32;
    const unsigned short* v_g = vws + (size_t)b * (NC * NN);

    // Q B-frags: lane holds Q[i = i0+il][c = ks*16 + h*8 + e], hi/lo
    bf16x8 qh[2], ql[2];
    {
        size_t qoff = bN32 + (size_t)(i0 + il) * 32 + h * 8;
        qh[0] = *(const bf16x8*)&qhi[qoff];
        ql[0] = *(const bf16x8*)&qlo[qoff];
        qh[1] = *(const bf16x8*)&qhi[qoff + 16];
        ql[1] = *(const bf16x8*)&qlo[qoff + 16];
    }

    // K A-frag row: S^T row (wjp*32+il) <-> global row kmap(il) (swap bits 2<->3)
    size_t krow;
    {
        int u = il;
        int kmp = (u & 0x13) | ((u & 4) << 1) | ((u & 8) >> 1);
        krow = ((size_t)(wjp * 32 + kmp) * 32) + h * 8;   // + j0*32 per jt
    }

    f32x16 acc[4];
#pragma unroll
    for (int fc = 0; fc < 4; ++fc)
#pragma unroll
        for (int e = 0; e < 16; ++e) acc[fc][e] = 0.f;
    float m_run = -3.0e38f, l_part = 0.f;   // per lane: q-row i = il

    // K register fetch for tile jt: [0,1]=hi ks0/1, [2,3]=lo ks0/1
    auto kfetch = [&](int jt, bf16x8* kr) {
        const size_t rb = krow + (size_t)(jt << 6) * 32;
        kr[0] = *(const bf16x8*)&kh_g[rb];
        kr[1] = *(const bf16x8*)&kh_g[rb + 16];
        kr[2] = *(const bf16x8*)&kl_g[rb];
        kr[3] = *(const bf16x8*)&kl_g[rb + 16];
    };
    // V register fetch for tile jt (V' layout: [jg][c][8]): vr[fc*2+ks]
    auto vfetch = [&](int jt, bf16x8* vr) {
#pragma unroll
        for (int fc = 0; fc < 4; ++fc)
#pragma unroll
            for (int ks = 0; ks < 2; ++ks) {
                const int c = wc * 128 + fc * 32 + il;
                const size_t jg = (size_t)(jt * 8 + wjp * 4 + ks * 2 + h);
                vr[fc * 2 + ks] = *(const bf16x8*)&v_g[(jg * NC + c) * 8];
            }
    };

    bf16x8 kreg[2][4];
    kfetch(0, kreg[0]);

#pragma unroll 2
    for (int jt = 0; jt < NN / 64; ++jt) {
        const int cb = jt & 1;
        bf16x8 vreg[8];
        vfetch(jt, vreg);                        // lands under QK + softmax
        if (jt < NN / 64 - 1) kfetch(jt + 1, kreg[cb ^ 1]);

        // ---- S^T = K·Q (32x32, hi/lo, log2 domain): D[j-row][i = il] ----
        f32x16 s2;
#pragma unroll
        for (int e = 0; e < 16; ++e) s2[e] = 0.f;
#pragma unroll
        for (int ks = 0; ks < 2; ++ks) {
            s2 = MFMA32(kreg[cb][2 + ks], qh[ks], s2);
            s2 = MFMA32(kreg[cb][ks], ql[ks], s2);
            s2 = MFMA32(kreg[cb][ks], qh[ks], s2);
        }

        // ---- online softmax (row i = il; halves combined via xor-32) ----
        float tl = s2[0];
#pragma unroll
        for (int e = 1; e < 16; ++e) tl = fmaxf(tl, s2[e]);
        tl = fmaxf(tl, __shfl_xor(tl, 32));

        if (!__all(tl <= m_run + 11.0f)) {
            float nm = fmaxf(m_run, tl);
            float rs = exp2_hw(m_run - nm);
            m_run = nm;
            l_part *= rs;
#pragma unroll
            for (int fc = 0; fc < 4; ++fc)
#pragma unroll
                for (int e = 0; e < 16; ++e) acc[fc][e] *= rs;
        }

        float p[16];
#pragma unroll
        for (int e = 0; e < 16; ++e) p[e] = exp2_hw(s2[e] - m_run);
        float ls = 0.f;
#pragma unroll
        for (int e = 0; e < 16; ++e) ls += p[e];
        ls += __shfl_xor(ls, 32);
        l_part += ls;

        // ---- P -> bf16 B-frags (j-order correct via kmap) ----
        bf16x8 pa[2];
#pragma unroll
        for (int ks = 0; ks < 2; ++ks) {
            u32x4 pw;
            pw[0] = cvtpk_bf16(p[ks * 8 + 0], p[ks * 8 + 1]);
            pw[1] = cvtpk_bf16(p[ks * 8 + 2], p[ks * 8 + 3]);
            pw[2] = cvtpk_bf16(p[ks * 8 + 4], p[ks * 8 + 5]);
            pw[3] = cvtpk_bf16(p[ks * 8 + 6], p[ks * 8 + 7]);
            pa[ks] = __builtin_bit_cast(bf16x8, pw);
        }

        // ---- PV: acc[fc] = V[c][j] (A) x P[j][i] (B), D[c-row][i-col] ----
#pragma unroll
        for (int fc = 0; fc < 4; ++fc) {
#pragma unroll
            for (int ks = 0; ks < 2; ++ks)
                acc[fc] = MFMA32(vreg[fc * 2 + ks], pa[ks], acc[fc]);
        }
    }

    // ---- merge wjp partials, normalize, residual-add, store ----
    float* ml = (float*)(smem + 65536);       // m: [w*32+i], l: [128 + w*32+i]
    if (lane < 32) {
        ml[w * 32 + il] = m_run;
        ml[128 + w * 32 + il] = l_part;
    }
    __syncthreads();

    const int wp = w ^ 2;                     // partner wave (wjp flipped)
    float m_o = ml[wp * 32 + il];
    float l_o = ml[128 + wp * 32 + il];
    float m_g = fmaxf(m_run, m_o);
    float a_s = exp2_hw(m_run - m_g);
    float l_tot = l_part * a_s + l_o * exp2_hw(m_o - m_g);
#pragma unroll
    for (int fc = 0; fc < 4; ++fc)
#pragma unroll
        for (int e = 0; e < 16; ++e) acc[fc][e] *= a_s;

    float* AB = (float*)smem;                 // [256 c][32 i]
    if (wjp == 1) {
#pragma unroll
        for (int fc = 0; fc < 4; ++fc)
#pragma unroll
            for (int e = 0; e < 16; ++e) {
                int c = wc * 128 + fc * 32 + (e & 3) + 8 * (e >> 2) + 4 * h;
                AB[c * 32 + il] = acc[fc][e];
            }
    }
    __syncthreads();

    float* ep = (float*)(smem + 32768);       // [256 c][32 i]
    if (wjp == 0) {
        const float gm = gamma_p[0];
        const float linv = gm / l_tot;
#pragma unroll
        for (int fc = 0; fc < 4; ++fc)
#pragma unroll
            for (int e = 0; e < 16; ++e) {
                int c = wc * 128 + fc * 32 + (e & 3) + 8 * (e >> 2) + 4 * h;
                ep[c * 32 + il] = (acc[fc][e] + AB[c * 32 + il]) * linv;
            }
    }
    __syncthreads();

    const float* xb = x + ((size_t)b << 20);
    float* ob = out + ((size_t)b << 20);
#pragma unroll
    for (int it = 0; it < 8; ++it) {
        int c = (t >> 3) + (it << 5);
        int j = t & 7;
        f32x4 v = *(const f32x4*)&ep[c * 32 + j * 4];
        f32x4 xv = *(const f32x4*)&xb[((size_t)c << 12) + i0 + j * 4];
        v += xv;
        *(f32x4*)&ob[((size_t)c << 12) + i0 + j * 4] = v;
    }
}

// ---------------------------------------------------------------------------
extern "C" void kernel_launch(void* const* d_in, const int* in_sizes, int n_in,
                              void* d_out, int out_size, void* d_ws, size_t ws_size,
                              hipStream_t stream)
{
    (void)in_sizes; (void)n_in; (void)out_size; (void)ws_size;
    const float* x = (const float*)d_in[0];
    const float* wq = (const float*)d_in[1];
    const float* qg = (const float*)d_in[2];
    const float* qb = (const float*)d_in[3];
    const float* qm = (const float*)d_in[4];
    const float* qv = (const float*)d_in[5];
    const float* wk = (const float*)d_in[6];
    const float* kg = (const float*)d_in[7];
    const float* kb = (const float*)d_in[8];
    const float* km = (const float*)d_in[9];
    const float* kv = (const float*)d_in[10];
    const float* wv = (const float*)d_in[11];
    const float* vg = (const float*)d_in[12];
    const float* vb = (const float*)d_in[13];
    const float* vm = (const float*)d_in[14];
    const float* vv = (const float*)d_in[15];
    const float* gamma = (const float*)d_in[16];

    unsigned short* ws = (unsigned short*)d_ws;
    const size_t QK = (size_t)NB * NN * 32;
    unsigned short* qhi = ws;
    unsigned short* qlo = ws + QK;
    unsigned short* khi = ws + 2 * QK;
    unsigned short* klo = ws + 3 * QK;
    unsigned short* vws = ws + 4 * QK;

    proj_kernel<<<dim3(512), dim3(256), 0, stream>>>(
        x, wq, qg, qb, qm, qv, wk, kg, kb, km, kv, wv, vg, vb, vm, vv,
        qhi, qlo, khi, klo, vws);
    attn_kernel<<<dim3(512), dim3(256), 0, stream>>>(
        x, gamma, qhi, qlo, khi, klo, vws, (float*)d_out);
}